// Round 1
// baseline (267.529 us; speedup 1.0000x reference)
//
#include <hip/hip_runtime.h>

// ---------- types ----------
typedef short bf16x8 __attribute__((ext_vector_type(8)));   // 8 bf16 = 4 VGPR (MFMA A/B frag)
typedef short s16x4  __attribute__((ext_vector_type(4)));   // 4 bf16 packed store
typedef float fx4    __attribute__((ext_vector_type(4)));   // MFMA C/D frag

#if __has_builtin(__builtin_amdgcn_exp2f)
#define EXP2 __builtin_amdgcn_exp2f
#else
#define EXP2 exp2f
#endif

// fp32 -> bf16 round-to-nearest-even (finite inputs only)
__device__ __forceinline__ short f2b(float f) {
  unsigned u = __float_as_uint(f);
  u = (u + 0x7fffu + ((u >> 16) & 1u)) >> 16;
  return (short)u;
}

// async global->LDS, 16B per lane. LDS dest = wave-uniform base + lane*16.
__device__ __forceinline__ void gld16(const void* g, void* l) {
  __builtin_amdgcn_global_load_lds(
      (const __attribute__((address_space(1))) unsigned int*)g,
      (__attribute__((address_space(3))) unsigned int*)l, 16, 0, 0);
}

// ---------- prep: x fp32 -> bf16 ----------
__global__ __launch_bounds__(256) void cvt_x_kernel(const float* __restrict__ x,
                                                    short* __restrict__ xb, int n4) {
  int i = blockIdx.x * blockDim.x + threadIdx.x;
  if (i < n4) {
    const float* s = x + (size_t)i * 4;
    s16x4 o = { f2b(s[0]), f2b(s[1]), f2b(s[2]), f2b(s[3]) };
    *(s16x4*)(xb + (size_t)i * 4) = o;
  }
}

// ---------- prep: weight transpose (+concat, + scale fold for Wq) ----------
// mode 0: outT[1536][512] = concat(Wq*qscale, Wkv)^T ; mode 1: outT[512][512] = Wo^T
__global__ __launch_bounds__(256) void prep_w_kernel(const float* __restrict__ W1,
                                                     const float* __restrict__ W2,
                                                     short* __restrict__ outT,
                                                     int mode, float qscale) {
  __shared__ float t[32][33];
  const int ct = blockIdx.x * 32, kt = blockIdx.y * 32;
  const int tx = threadIdx.x, ty = threadIdx.y;
#pragma unroll
  for (int s = 0; s < 4; ++s) {
    int k = kt + ty + s * 8;
    int c = ct + tx;
    float v;
    if (mode == 0) v = (c < 512) ? W1[(size_t)k * 512 + c] * qscale
                                 : W2[(size_t)k * 1024 + (c - 512)];
    else           v = W1[(size_t)k * 512 + c];
    t[ty + s * 8][tx] = v;
  }
  __syncthreads();
#pragma unroll
  for (int s = 0; s < 4; ++s) {
    int c = ct + ty + s * 8;
    int k = kt + tx;
    outT[(size_t)c * 512 + k] = f2b(t[tx][ty + s * 8]);
  }
}

// ---------- m97-style 128x128 GEMM, A[M,K] bf16 row-major, Bt[N,K] bf16 row-major ----------
// MODE 0: QKV epilogue -> q/k [b,h,n,64] bf16, v transposed [b,h,64,n] bf16
// MODE 1: fp32 + bias -> out [M,N]
template <int MODE>
__global__ __launch_bounds__(256) void gemm128(
    const short* __restrict__ A, const short* __restrict__ Bt,
    int M, int N, int K,
    short* __restrict__ oq, short* __restrict__ ok, short* __restrict__ ovT,
    float* __restrict__ of, const float* __restrict__ bias) {
  __shared__ short As[128 * 32];
  __shared__ short Bs[128 * 32];
  const int tid = threadIdx.x;
  const int wave = tid >> 6, lane = tid & 63;
  const int quad = lane >> 4, l15 = lane & 15;
  const int wm = wave >> 1, wn = wave & 1;
  const int m0 = blockIdx.y * 128, n0 = blockIdx.x * 128;

  fx4 acc[4][4];
#pragma unroll
  for (int i = 0; i < 4; ++i)
#pragma unroll
    for (int j = 0; j < 4; ++j) acc[i][j] = fx4{0.f, 0.f, 0.f, 0.f};

  for (int k0 = 0; k0 < K; k0 += 32) {
#pragma unroll
    for (int c = 0; c < 2; ++c) {
      int idx = (wave * 2 + c) * 64 + lane;  // 0..511
      int mr = idx >> 2, kk = (idx & 3) * 8;
      gld16(A  + (size_t)(m0 + mr) * K + k0 + kk, As + (wave * 2 + c) * 512);
      gld16(Bt + (size_t)(n0 + mr) * K + k0 + kk, Bs + (wave * 2 + c) * 512);
    }
    __syncthreads();
    bf16x8 af[4], bfr[4];
#pragma unroll
    for (int i = 0; i < 4; ++i)
      af[i] = *(const bf16x8*)(As + (wm * 64 + i * 16 + l15) * 32 + quad * 8);
#pragma unroll
    for (int i = 0; i < 4; ++i)
      bfr[i] = *(const bf16x8*)(Bs + (wn * 64 + i * 16 + l15) * 32 + quad * 8);
#pragma unroll
    for (int mi = 0; mi < 4; ++mi)
#pragma unroll
      for (int ni = 0; ni < 4; ++ni)
        acc[mi][ni] = __builtin_amdgcn_mfma_f32_16x16x32_bf16(af[mi], bfr[ni], acc[mi][ni], 0, 0, 0);
    __syncthreads();
  }

  const int rowb = m0 + wm * 64;
  const int colb = n0 + wn * 64;
  if (MODE == 0) {
    const int cls = n0 >> 9;  // 0=q cols, 1=k cols, 2=v cols (uniform per block)
#pragma unroll
    for (int mi = 0; mi < 4; ++mi) {
      int rbase = rowb + mi * 16 + quad * 4;  // +r ; 4 consecutive rows, same batch
      int bb = rbase >> 11;
      int ii = rbase & 2047;
#pragma unroll
      for (int ni = 0; ni < 4; ++ni) {
        int cg = colb + ni * 16 + l15;
        int c = cg & 511;
        int hh = c >> 6, dd = c & 63;
        if (cls < 2) {
          short* dst = (cls == 0 ? oq : ok) + ((size_t)(bb * 8 + hh) * 2048 + ii) * 64 + dd;
          dst[0]   = f2b(acc[mi][ni][0]);
          dst[64]  = f2b(acc[mi][ni][1]);
          dst[128] = f2b(acc[mi][ni][2]);
          dst[192] = f2b(acc[mi][ni][3]);
        } else {
          s16x4 v4 = { f2b(acc[mi][ni][0]), f2b(acc[mi][ni][1]),
                       f2b(acc[mi][ni][2]), f2b(acc[mi][ni][3]) };
          *(s16x4*)(ovT + ((size_t)(bb * 8 + hh) * 64 + dd) * 2048 + ii) = v4;
        }
      }
    }
  } else {
#pragma unroll
    for (int mi = 0; mi < 4; ++mi)
#pragma unroll
      for (int ni = 0; ni < 4; ++ni) {
        int cg = colb + ni * 16 + l15;
        float bv = bias[cg];
#pragma unroll
        for (int r = 0; r < 4; ++r) {
          int rg = rowb + mi * 16 + quad * 4 + r;
          of[(size_t)rg * N + cg] = acc[mi][ni][r] + bv;
        }
      }
  }
}

// ---------- flash attention ----------
// Q,K: [bh=32][2048][64] bf16 ; Vt: [bh][64][2048] bf16 ; O: [b][2048][512] bf16
// grid (16 qtiles, 32 bh), 256 threads (4 waves x 32 Q-rows). Logits already in
// log2 units (SCALE*log2e folded into Wq) -> softmax via exp2.
__global__ __launch_bounds__(256) void attn_kernel(
    const short* __restrict__ Q, const short* __restrict__ K,
    const short* __restrict__ Vt, short* __restrict__ O) {
  __shared__ short Ks[64][72];       // K tile [j][d], +8 pad (stride 144B -> 2-way max)
  __shared__ short Vs[64][72];       // V^T tile [d][j]
  __shared__ short Ps[4][32][72];    // per-wave P (C-layout -> A-layout via LDS)

  const int tid = threadIdx.x;
  const int wave = tid >> 6, lane = tid & 63;
  const int quad = lane >> 4, l15 = lane & 15;
  const int bh = blockIdx.y;
  const int b = bh >> 3, h = bh & 7;
  const int i0 = blockIdx.x * 128;
  const int iw = i0 + wave * 32;

  // Q fragments, held in registers for the whole kernel
  bf16x8 qf[2][2];
#pragma unroll
  for (int mi = 0; mi < 2; ++mi)
#pragma unroll
    for (int ks = 0; ks < 2; ++ks)
      qf[mi][ks] = *(const bf16x8*)(Q + ((size_t)bh * 2048 + iw + mi * 16 + l15) * 64 + ks * 32 + quad * 8);

  fx4 oacc[2][4];
  float m_r[2][4], l_r[2][4];
#pragma unroll
  for (int mi = 0; mi < 2; ++mi) {
#pragma unroll
    for (int nd = 0; nd < 4; ++nd) oacc[mi][nd] = fx4{0.f, 0.f, 0.f, 0.f};
#pragma unroll
    for (int r = 0; r < 4; ++r) { m_r[mi][r] = -1e30f; l_r[mi][r] = 0.f; }
  }

  for (int j0 = 0; j0 < 2048; j0 += 64) {
    // stage K tile and V^T tile (vector loads; padded LDS rows stay 16B-aligned)
#pragma unroll
    for (int t = 0; t < 2; ++t) {
      int idx = tid + t * 256;             // 0..511
      int row = idx >> 3, seg = idx & 7;
      *(bf16x8*)(&Ks[row][seg * 8]) =
          *(const bf16x8*)(K + ((size_t)bh * 2048 + j0 + row) * 64 + seg * 8);
      *(bf16x8*)(&Vs[row][seg * 8]) =
          *(const bf16x8*)(Vt + ((size_t)bh * 64 + row) * 2048 + j0 + seg * 8);
    }
    __syncthreads();

    // S = Q K^T  (already includes scale*log2e)
    fx4 s[2][4];
#pragma unroll
    for (int mi = 0; mi < 2; ++mi)
#pragma unroll
      for (int nj = 0; nj < 4; ++nj) s[mi][nj] = fx4{0.f, 0.f, 0.f, 0.f};
#pragma unroll
    for (int ks = 0; ks < 2; ++ks) {
      bf16x8 kf[4];
#pragma unroll
      for (int nj = 0; nj < 4; ++nj)
        kf[nj] = *(const bf16x8*)(&Ks[nj * 16 + l15][ks * 32 + quad * 8]);
#pragma unroll
      for (int mi = 0; mi < 2; ++mi)
#pragma unroll
        for (int nj = 0; nj < 4; ++nj)
          s[mi][nj] = __builtin_amdgcn_mfma_f32_16x16x32_bf16(qf[mi][ks], kf[nj], s[mi][nj], 0, 0, 0);
    }

    // online softmax (rows = quad*4+r per C-layout; reduce across the 16-lane col group)
#pragma unroll
    for (int mi = 0; mi < 2; ++mi) {
#pragma unroll
      for (int r = 0; r < 4; ++r) {
        float mx = fmaxf(fmaxf(s[mi][0][r], s[mi][1][r]), fmaxf(s[mi][2][r], s[mi][3][r]));
#pragma unroll
        for (int off = 8; off >= 1; off >>= 1) mx = fmaxf(mx, __shfl_xor(mx, off));
        float mnew = fmaxf(m_r[mi][r], mx);
        float alpha = EXP2(m_r[mi][r] - mnew);
        m_r[mi][r] = mnew;
        float ps = 0.f;
#pragma unroll
        for (int nj = 0; nj < 4; ++nj) {
          float p = EXP2(s[mi][nj][r] - mnew);
          s[mi][nj][r] = p;
          ps += p;
        }
#pragma unroll
        for (int off = 8; off >= 1; off >>= 1) ps += __shfl_xor(ps, off);
        l_r[mi][r] = l_r[mi][r] * alpha + ps;
#pragma unroll
        for (int nd = 0; nd < 4; ++nd) oacc[mi][nd][r] *= alpha;
      }
    }

    // P (bf16) -> per-wave LDS (C-layout write, A-layout read; wave-private, no barrier)
#pragma unroll
    for (int mi = 0; mi < 2; ++mi)
#pragma unroll
      for (int nj = 0; nj < 4; ++nj)
#pragma unroll
        for (int r = 0; r < 4; ++r)
          Ps[wave][mi * 16 + quad * 4 + r][nj * 16 + l15] = f2b(s[mi][nj][r]);

    // O += P V
#pragma unroll
    for (int kj = 0; kj < 2; ++kj) {
      bf16x8 af[2], vf[4];
#pragma unroll
      for (int mi = 0; mi < 2; ++mi)
        af[mi] = *(const bf16x8*)(&Ps[wave][mi * 16 + l15][kj * 32 + quad * 8]);
#pragma unroll
      for (int nd = 0; nd < 4; ++nd)
        vf[nd] = *(const bf16x8*)(&Vs[nd * 16 + l15][kj * 32 + quad * 8]);
#pragma unroll
      for (int mi = 0; mi < 2; ++mi)
#pragma unroll
        for (int nd = 0; nd < 4; ++nd)
          oacc[mi][nd] = __builtin_amdgcn_mfma_f32_16x16x32_bf16(af[mi], vf[nd], oacc[mi][nd], 0, 0, 0);
    }
    __syncthreads();
  }

  // normalize + write O as bf16 [b, n, h*64+d]
#pragma unroll
  for (int mi = 0; mi < 2; ++mi) {
    float inv[4];
#pragma unroll
    for (int r = 0; r < 4; ++r) inv[r] = __builtin_amdgcn_rcpf(l_r[mi][r]);
#pragma unroll
    for (int nd = 0; nd < 4; ++nd) {
      int dd = nd * 16 + l15;
#pragma unroll
      for (int r = 0; r < 4; ++r) {
        int ii = iw + mi * 16 + quad * 4 + r;
        O[((size_t)b * 2048 + ii) * 512 + h * 64 + dd] = f2b(oacc[mi][nd][r] * inv[r]);
      }
    }
  }
}

// ---------- launch ----------
extern "C" void kernel_launch(void* const* d_in, const int* in_sizes, int n_in,
                              void* d_out, int out_size, void* d_ws, size_t ws_size,
                              hipStream_t stream) {
  const float* x   = (const float*)d_in[0];
  const float* Wq  = (const float*)d_in[1];
  const float* Wkv = (const float*)d_in[2];
  const float* Wo  = (const float*)d_in[3];
  const float* bo  = (const float*)d_in[4];
  float* out = (float*)d_out;

  char* p = (char*)d_ws;
  short* xb    = (short*)p; p += (size_t)8192 * 512 * 2;   // x bf16 [8192,512]
  short* WallT = (short*)p; p += (size_t)1536 * 512 * 2;   // [Wq|Wkv]^T bf16 [1536,512]
  short* WoT   = (short*)p; p += (size_t)512 * 512 * 2;    // Wo^T bf16 [512,512]
  short* qb    = (short*)p; p += (size_t)32 * 2048 * 64 * 2;  // [bh,n,d]
  short* kb    = (short*)p; p += (size_t)32 * 2048 * 64 * 2;  // [bh,n,d]
  short* vTb   = (short*)p; p += (size_t)32 * 64 * 2048 * 2;  // [bh,d,n]
  short* Ob    = (short*)p; p += (size_t)8192 * 512 * 2;   // attn out bf16 [8192,512]

  const float qscale = 0.125f * 1.4426950408889634f;  // d^-0.5 * log2(e)

  cvt_x_kernel<<<4096, 256, 0, stream>>>(x, xb, 1048576);
  dim3 tb(32, 8);
  prep_w_kernel<<<dim3(48, 16), tb, 0, stream>>>(Wq, Wkv, WallT, 0, qscale);
  prep_w_kernel<<<dim3(16, 16), tb, 0, stream>>>(Wo, nullptr, WoT, 1, 1.f);
  gemm128<0><<<dim3(12, 64), 256, 0, stream>>>(xb, WallT, 8192, 1536, 512,
                                               qb, kb, vTb, nullptr, nullptr);
  attn_kernel<<<dim3(16, 32), 256, 0, stream>>>(qb, kb, vTb, Ob);
  gemm128<1><<<dim3(4, 64), 256, 0, stream>>>(Ob, WoT, 8192, 512, 512,
                                              nullptr, nullptr, nullptr, out, bo);
}

// Round 2
// 196.879 us; speedup vs baseline: 1.3588x; 1.3588x over previous
//
#include <hip/hip_runtime.h>

// ---------- types ----------
typedef short bf16x8 __attribute__((ext_vector_type(8)));   // 8 bf16 = 4 VGPR (MFMA A/B frag)
typedef short s16x4  __attribute__((ext_vector_type(4)));   // 4 bf16 packed store
typedef float fx4    __attribute__((ext_vector_type(4)));   // MFMA C/D frag

#if __has_builtin(__builtin_amdgcn_exp2f)
#define EXP2 __builtin_amdgcn_exp2f
#else
#define EXP2 exp2f
#endif

// fp32 -> bf16 round-to-nearest-even (finite inputs only)
__device__ __forceinline__ short f2b(float f) {
  unsigned u = __float_as_uint(f);
  u = (u + 0x7fffu + ((u >> 16) & 1u)) >> 16;
  return (short)u;
}

// async global->LDS, 16B per lane. LDS dest = wave-uniform base + lane*16.
__device__ __forceinline__ void gld16(const void* g, void* l) {
  __builtin_amdgcn_global_load_lds(
      (const __attribute__((address_space(1))) unsigned int*)g,
      (__attribute__((address_space(3))) unsigned int*)l, 16, 0, 0);
}

// ---------- prep: x fp32 -> bf16 ----------
__global__ __launch_bounds__(256) void cvt_x_kernel(const float* __restrict__ x,
                                                    short* __restrict__ xb, int n4) {
  int i = blockIdx.x * blockDim.x + threadIdx.x;
  if (i < n4) {
    const float* s = x + (size_t)i * 4;
    s16x4 o = { f2b(s[0]), f2b(s[1]), f2b(s[2]), f2b(s[3]) };
    *(s16x4*)(xb + (size_t)i * 4) = o;
  }
}

// ---------- prep: weight transpose (+concat, + scale fold for Wq) ----------
// mode 0: outT[1536][512] = concat(Wq*qscale, Wkv)^T ; mode 1: outT[512][512] = Wo^T
__global__ __launch_bounds__(256) void prep_w_kernel(const float* __restrict__ W1,
                                                     const float* __restrict__ W2,
                                                     short* __restrict__ outT,
                                                     int mode, float qscale) {
  __shared__ float t[32][33];
  const int ct = blockIdx.x * 32, kt = blockIdx.y * 32;
  const int tx = threadIdx.x, ty = threadIdx.y;
#pragma unroll
  for (int s = 0; s < 4; ++s) {
    int k = kt + ty + s * 8;
    int c = ct + tx;
    float v;
    if (mode == 0) v = (c < 512) ? W1[(size_t)k * 512 + c] * qscale
                                 : W2[(size_t)k * 1024 + (c - 512)];
    else           v = W1[(size_t)k * 512 + c];
    t[ty + s * 8][tx] = v;
  }
  __syncthreads();
#pragma unroll
  for (int s = 0; s < 4; ++s) {
    int c = ct + ty + s * 8;
    int k = kt + tx;
    outT[(size_t)c * 512 + k] = f2b(t[tx][ty + s * 8]);
  }
}

// ---------- m97-style 128x128 GEMM, A[M,K] bf16 row-major, Bt[N,K] bf16 row-major ----------
// MODE 0: QKV epilogue -> q/k [b,h,n,64] bf16, v transposed [b,h,64,n] bf16
// MODE 1: fp32 + bias -> out [M,N]
template <int MODE>
__global__ __launch_bounds__(256) void gemm128(
    const short* __restrict__ A, const short* __restrict__ Bt,
    int M, int N, int K,
    short* __restrict__ oq, short* __restrict__ ok, short* __restrict__ ovT,
    float* __restrict__ of, const float* __restrict__ bias) {
  __shared__ short As[128 * 32];
  __shared__ short Bs[128 * 32];
  const int tid = threadIdx.x;
  const int wave = tid >> 6, lane = tid & 63;
  const int quad = lane >> 4, l15 = lane & 15;
  const int wm = wave >> 1, wn = wave & 1;
  const int m0 = blockIdx.y * 128, n0 = blockIdx.x * 128;

  fx4 acc[4][4];
#pragma unroll
  for (int i = 0; i < 4; ++i)
#pragma unroll
    for (int j = 0; j < 4; ++j) acc[i][j] = fx4{0.f, 0.f, 0.f, 0.f};

  for (int k0 = 0; k0 < K; k0 += 32) {
#pragma unroll
    for (int c = 0; c < 2; ++c) {
      int idx = (wave * 2 + c) * 64 + lane;  // 0..511
      int mr = idx >> 2, kk = (idx & 3) * 8;
      gld16(A  + (size_t)(m0 + mr) * K + k0 + kk, As + (wave * 2 + c) * 512);
      gld16(Bt + (size_t)(n0 + mr) * K + k0 + kk, Bs + (wave * 2 + c) * 512);
    }
    __syncthreads();
    bf16x8 af[4], bfr[4];
#pragma unroll
    for (int i = 0; i < 4; ++i)
      af[i] = *(const bf16x8*)(As + (wm * 64 + i * 16 + l15) * 32 + quad * 8);
#pragma unroll
    for (int i = 0; i < 4; ++i)
      bfr[i] = *(const bf16x8*)(Bs + (wn * 64 + i * 16 + l15) * 32 + quad * 8);
#pragma unroll
    for (int mi = 0; mi < 4; ++mi)
#pragma unroll
      for (int ni = 0; ni < 4; ++ni)
        acc[mi][ni] = __builtin_amdgcn_mfma_f32_16x16x32_bf16(af[mi], bfr[ni], acc[mi][ni], 0, 0, 0);
    __syncthreads();
  }

  const int rowb = m0 + wm * 64;
  const int colb = n0 + wn * 64;
  if (MODE == 0) {
    const int cls = n0 >> 9;  // 0=q cols, 1=k cols, 2=v cols (uniform per block)
#pragma unroll
    for (int mi = 0; mi < 4; ++mi) {
      int rbase = rowb + mi * 16 + quad * 4;  // +r ; 4 consecutive rows, same batch
      int bb = rbase >> 11;
      int ii = rbase & 2047;
#pragma unroll
      for (int ni = 0; ni < 4; ++ni) {
        int cg = colb + ni * 16 + l15;
        int c = cg & 511;
        int hh = c >> 6, dd = c & 63;
        if (cls < 2) {
          short* dst = (cls == 0 ? oq : ok) + ((size_t)(bb * 8 + hh) * 2048 + ii) * 64 + dd;
          dst[0]   = f2b(acc[mi][ni][0]);
          dst[64]  = f2b(acc[mi][ni][1]);
          dst[128] = f2b(acc[mi][ni][2]);
          dst[192] = f2b(acc[mi][ni][3]);
        } else {
          s16x4 v4 = { f2b(acc[mi][ni][0]), f2b(acc[mi][ni][1]),
                       f2b(acc[mi][ni][2]), f2b(acc[mi][ni][3]) };
          *(s16x4*)(ovT + ((size_t)(bb * 8 + hh) * 64 + dd) * 2048 + ii) = v4;
        }
      }
    }
  } else {
#pragma unroll
    for (int mi = 0; mi < 4; ++mi)
#pragma unroll
      for (int ni = 0; ni < 4; ++ni) {
        int cg = colb + ni * 16 + l15;
        float bv = bias[cg];
#pragma unroll
        for (int r = 0; r < 4; ++r) {
          int rg = rowb + mi * 16 + quad * 4 + r;
          of[(size_t)rg * N + cg] = acc[mi][ni][r] + bv;
        }
      }
  }
}

// ---------- flash attention, S^T dataflow ----------
// Q,K: [bh=32][2048][64] bf16 ; Vt: [bh][64][2048] bf16 ; O: [b][2048][512] bf16
// grid (16 qtiles, 32 bh), 4 waves x 32 q-rows = 128 rows/block.
// Per wave: S^T[64 j][32 i] = K·Q^T ; softmax over j = per-lane(16) + shfl 16/32 ;
// P stored [i][j] (natural) -> B-operand of O^T[64 d][32 i] += V^T·P^T.
// K/V tiles staged via global_load_lds w/ XOR-seg swizzle (seg ^= row&7): no pad,
// conflict-free-ish b128 frag reads, zero staging VALU.
__global__ __launch_bounds__(256) void attn_kernel(
    const short* __restrict__ Q, const short* __restrict__ K,
    const short* __restrict__ Vt, short* __restrict__ O) {
  __shared__ short Ks[64 * 64];        // [j][d], seg-swizzled
  __shared__ short Vs[64 * 64];        // [d][j], seg-swizzled
  __shared__ short Ps[4 * 32 * 72];    // per-wave P[i][j], stride 72 (144B, 16B-aligned)

  const int tid = threadIdx.x;
  const int wave = tid >> 6, lane = tid & 63;
  const int quad = lane >> 4, l15 = lane & 15;
  const int bh = blockIdx.y;
  const int b = bh >> 3, h = bh & 7;
  const int i0 = blockIdx.x * 128 + wave * 32;
  short* Pw = Ps + wave * (32 * 72);

  // Q as B-operand fragments (held all kernel): B[k=d][n=i], lane: i=it*16+l15, d=ks*32+quad*8+idx
  bf16x8 qf[2][2];
#pragma unroll
  for (int it = 0; it < 2; ++it)
#pragma unroll
    for (int ks = 0; ks < 2; ++ks)
      qf[it][ks] = *(const bf16x8*)(Q + ((size_t)bh * 2048 + i0 + it * 16 + l15) * 64 + ks * 32 + quad * 8);

  fx4 oacc[4][2];                      // O^T [dt][it]: row d=quad*4+r, col i=l15
  float m_s[2] = {-1e30f, -1e30f};
  float l_s[2] = {0.f, 0.f};
#pragma unroll
  for (int dt = 0; dt < 4; ++dt)
#pragma unroll
    for (int it = 0; it < 2; ++it) oacc[dt][it] = fx4{0.f, 0.f, 0.f, 0.f};

  for (int j0 = 0; j0 < 2048; j0 += 64) {
    // ---- stage K tile [64 j][64 d] and V^T tile [64 d][64 j], swizzled, async ----
#pragma unroll
    for (int t = 0; t < 2; ++t) {
      int idx = t * 256 + tid;           // 0..511 ; 16B units
      int row = idx >> 3;
      int sg = (idx & 7) ^ (row & 7);
      gld16(K  + ((size_t)bh * 2048 + j0 + row) * 64 + sg * 8,
            Ks + (size_t)(t * 256 + wave * 64) * 8);
      gld16(Vt + ((size_t)bh * 64 + row) * 2048 + j0 + sg * 8,
            Vs + (size_t)(t * 256 + wave * 64) * 8);
    }
    __syncthreads();

    // ---- S^T = K · Q^T (scale*log2e folded into Wq) ----
    fx4 s[4][2];
#pragma unroll
    for (int jt = 0; jt < 4; ++jt)
#pragma unroll
      for (int it = 0; it < 2; ++it) s[jt][it] = fx4{0.f, 0.f, 0.f, 0.f};
#pragma unroll
    for (int ks = 0; ks < 2; ++ks) {
      bf16x8 kf[4];
#pragma unroll
      for (int jt = 0; jt < 4; ++jt)
        kf[jt] = *(const bf16x8*)(Ks + (jt * 16 + l15) * 64 + (((ks * 4 + quad) ^ (l15 & 7)) * 8));
#pragma unroll
      for (int jt = 0; jt < 4; ++jt)
#pragma unroll
        for (int it = 0; it < 2; ++it)
          s[jt][it] = __builtin_amdgcn_mfma_f32_16x16x32_bf16(kf[jt], qf[it][ks], s[jt][it], 0, 0, 0);
    }

    // ---- online softmax over j (per-lane 16 vals + shfl across quads) ----
#pragma unroll
    for (int it = 0; it < 2; ++it) {
      float mx = s[0][it][0];
#pragma unroll
      for (int jt = 0; jt < 4; ++jt)
#pragma unroll
        for (int r = 0; r < 4; ++r) mx = fmaxf(mx, s[jt][it][r]);
      mx = fmaxf(mx, __shfl_xor(mx, 16));
      mx = fmaxf(mx, __shfl_xor(mx, 32));
      float mnew = fmaxf(m_s[it], mx);
      float alpha = EXP2(m_s[it] - mnew);
      m_s[it] = mnew;
      float ps = 0.f;
#pragma unroll
      for (int jt = 0; jt < 4; ++jt)
#pragma unroll
        for (int r = 0; r < 4; ++r) {
          float p = EXP2(s[jt][it][r] - mnew);
          s[jt][it][r] = p;
          ps += p;
        }
      ps += __shfl_xor(ps, 16);
      ps += __shfl_xor(ps, 32);
      l_s[it] = l_s[it] * alpha + ps;
#pragma unroll
      for (int dt = 0; dt < 4; ++dt) oacc[dt][it] *= alpha;
      // P -> per-wave LDS, natural [i][j]: lane owns 4 consecutive j per (jt) -> b64 write
#pragma unroll
      for (int jt = 0; jt < 4; ++jt) {
        s16x4 pk = { f2b(s[jt][it][0]), f2b(s[jt][it][1]),
                     f2b(s[jt][it][2]), f2b(s[jt][it][3]) };
        *(s16x4*)(Pw + (it * 16 + l15) * 72 + jt * 16 + quad * 4) = pk;
      }
    }

    // ---- O^T += V^T · P^T ----
#pragma unroll
    for (int kj = 0; kj < 2; ++kj) {
      bf16x8 vf[4], pf[2];
#pragma unroll
      for (int dt = 0; dt < 4; ++dt)
        vf[dt] = *(const bf16x8*)(Vs + (dt * 16 + l15) * 64 + (((kj * 4 + quad) ^ (l15 & 7)) * 8));
#pragma unroll
      for (int it = 0; it < 2; ++it)
        pf[it] = *(const bf16x8*)(Pw + (it * 16 + l15) * 72 + kj * 32 + quad * 8);
#pragma unroll
      for (int dt = 0; dt < 4; ++dt)
#pragma unroll
        for (int it = 0; it < 2; ++it)
          oacc[dt][it] = __builtin_amdgcn_mfma_f32_16x16x32_bf16(vf[dt], pf[it], oacc[dt][it], 0, 0, 0);
    }
    __syncthreads();
  }

  // ---- normalize + write O bf16 [b][n=i][h*64+d]; lane owns 4 consecutive d -> b64 ----
#pragma unroll
  for (int it = 0; it < 2; ++it) {
    float inv = __builtin_amdgcn_rcpf(l_s[it]);
    size_t rowbase = ((size_t)b * 2048 + i0 + it * 16 + l15) * 512 + h * 64;
#pragma unroll
    for (int dt = 0; dt < 4; ++dt) {
      s16x4 o4 = { f2b(oacc[dt][it][0] * inv), f2b(oacc[dt][it][1] * inv),
                   f2b(oacc[dt][it][2] * inv), f2b(oacc[dt][it][3] * inv) };
      *(s16x4*)(O + rowbase + dt * 16 + quad * 4) = o4;
    }
  }
}

// ---------- launch ----------
extern "C" void kernel_launch(void* const* d_in, const int* in_sizes, int n_in,
                              void* d_out, int out_size, void* d_ws, size_t ws_size,
                              hipStream_t stream) {
  const float* x   = (const float*)d_in[0];
  const float* Wq  = (const float*)d_in[1];
  const float* Wkv = (const float*)d_in[2];
  const float* Wo  = (const float*)d_in[3];
  const float* bo  = (const float*)d_in[4];
  float* out = (float*)d_out;

  char* p = (char*)d_ws;
  short* xb    = (short*)p; p += (size_t)8192 * 512 * 2;   // x bf16 [8192,512]
  short* WallT = (short*)p; p += (size_t)1536 * 512 * 2;   // [Wq|Wkv]^T bf16 [1536,512]
  short* WoT   = (short*)p; p += (size_t)512 * 512 * 2;    // Wo^T bf16 [512,512]
  short* qb    = (short*)p; p += (size_t)32 * 2048 * 64 * 2;  // [bh,n,d]
  short* kb    = (short*)p; p += (size_t)32 * 2048 * 64 * 2;  // [bh,n,d]
  short* vTb   = (short*)p; p += (size_t)32 * 64 * 2048 * 2;  // [bh,d,n]
  short* Ob    = (short*)p; p += (size_t)8192 * 512 * 2;   // attn out bf16 [8192,512]

  const float qscale = 0.125f * 1.4426950408889634f;  // d^-0.5 * log2(e)

  cvt_x_kernel<<<4096, 256, 0, stream>>>(x, xb, 1048576);
  dim3 tb(32, 8);
  prep_w_kernel<<<dim3(48, 16), tb, 0, stream>>>(Wq, Wkv, WallT, 0, qscale);
  prep_w_kernel<<<dim3(16, 16), tb, 0, stream>>>(Wo, nullptr, WoT, 1, 1.f);
  gemm128<0><<<dim3(12, 64), 256, 0, stream>>>(xb, WallT, 8192, 1536, 512,
                                               qb, kb, vTb, nullptr, nullptr);
  attn_kernel<<<dim3(16, 32), 256, 0, stream>>>(qb, kb, vTb, Ob);
  gemm128<1><<<dim3(4, 64), 256, 0, stream>>>(Ob, WoT, 8192, 512, 512,
                                              nullptr, nullptr, nullptr, out, bo);
}